// Round 4
// baseline (176.719 us; speedup 1.0000x reference)
//
#include <hip/hip_runtime.h>

#define BATCH 4096
#define D_IN 1024
#define D_OUT 1024
#define N_EXPERTS 8

#define TM 64
#define TN 128
#define MAX_TILES 71   // sum ceil(c_e/64) <= 64 + 7

// ws int32 slots (metadata)
#define WS_PERM    0       // [4096]
#define WS_STARTS  4096    // [9]
#define WS_TILE_E  4112    // [71]
#define WS_TILE_M  4200    // [71]
#define WS_NTILES  4288    // [1]

// ws byte offsets (bf16 planes)
#define OFF_WHI  32768
#define SZ_WPL   (8u*1024u*1024u*2u)        // 16 MB per W plane (8M shorts)
#define OFF_WLO  (OFF_WHI + SZ_WPL)
#define OFF_XHI  (OFF_WLO + SZ_WPL)
#define SZ_XPL   (4u*1024u*1024u*2u)        // 8 MB per xs plane
#define OFF_XLO  (OFF_XHI + SZ_XPL)
#define WS_NEED  ((size_t)OFF_XLO + SZ_XPL) // ~48 MB + 32 KB

#define W_CHUNKS (N_EXPERTS * 64 * 32 * 64) // 1,048,576 16B-chunks
#define X_CHUNKS (BATCH * 128)              // 524,288 8-elem chunks

typedef __attribute__((ext_vector_type(8))) short short8;   // 8 x bf16
typedef __attribute__((ext_vector_type(4))) float f32x4;

// ---------------------------------------------------------------------------
__global__ void group_kernel(const int* __restrict__ actions, int* __restrict__ ws) {
    __shared__ int cnt[N_EXPERTS];
    __shared__ int base[N_EXPERTS];
    const int t = threadIdx.x;
    if (t < N_EXPERTS) cnt[t] = 0;
    __syncthreads();
    for (int i = t; i < BATCH; i += 256) atomicAdd(&cnt[actions[i]], 1);
    __syncthreads();
    if (t == 0) {
        int s = 0, nt = 0;
        for (int e = 0; e < N_EXPERTS; ++e) {
            const int c = cnt[e];
            base[e] = s;
            ws[WS_STARTS + e] = s;
            for (int m0 = 0; m0 < c; m0 += TM) {
                ws[WS_TILE_E + nt] = e;
                ws[WS_TILE_M + nt] = m0;
                ++nt;
            }
            s += c;
            cnt[e] = 0;
        }
        ws[WS_STARTS + N_EXPERTS] = s;
        ws[WS_NTILES] = nt;
    }
    __syncthreads();
    for (int i = t; i < BATCH; i += 256) {
        const int a = actions[i];
        const int pos = base[a] + atomicAdd(&cnt[a], 1);
        ws[WS_PERM + pos] = i;
    }
}

// fp32 -> bf16 hi/lo split (truncation; lo captures next 8 mantissa bits)
__device__ __forceinline__ void cvt8(const float4 a, const float4 b,
                                     short8& h, short8& l) {
    float f[8] = {a.x, a.y, a.z, a.w, b.x, b.y, b.z, b.w};
#pragma unroll
    for (int i = 0; i < 8; ++i) {
        const unsigned u = __float_as_uint(f[i]);
        h[i] = (short)(u >> 16);
        const float r = f[i] - __uint_as_float(u & 0xffff0000u);
        l[i] = (short)(__float_as_uint(r) >> 16);
    }
}

// ---------------------------------------------------------------------------
// Preconvert: W -> fragment-tiled bf16 hi/lo planes; xs -> row-major planes.
// W chunk g: lane=g&63, s=(g>>6)&31, nt=(g>>11)&63, e=g>>17.
//   element (lane,j): W[e][nt*16+(lane&15)][s*32+(lane>>4)*8+j]
// This is EXACTLY the LDS fragment layout the GEMM DMAs per K-step.
// ---------------------------------------------------------------------------
__global__ __launch_bounds__(256) void convert_kernel(
    const float* __restrict__ xs, const float* __restrict__ W,
    unsigned short* __restrict__ whi, unsigned short* __restrict__ wlo,
    unsigned short* __restrict__ xhi, unsigned short* __restrict__ xlo)
{
    const int g = blockIdx.x * 256 + threadIdx.x;
    if (g < W_CHUNKS) {
        const int lane = g & 63, s = (g >> 6) & 31, nt = (g >> 11) & 63, e = g >> 17;
        const int n = nt * 16 + (lane & 15);
        const int k = s * 32 + ((lane >> 4) << 3);
        const float* src = W + ((size_t)e << 20) + (size_t)n * D_IN + k;
        const float4 v0 = *(const float4*)src;
        const float4 v1 = *(const float4*)(src + 4);
        short8 h, l;
        cvt8(v0, v1, h, l);
        ((short8*)whi)[g] = h;
        ((short8*)wlo)[g] = l;
    } else {
        const int gx = g - W_CHUNKS;   // < X_CHUNKS by grid construction
        const float* src = xs + (size_t)gx * 8;
        const float4 v0 = *(const float4*)src;
        const float4 v1 = *(const float4*)(src + 4);
        short8 h, l;
        cvt8(v0, v1, h, l);
        ((short8*)xhi)[gx] = h;
        ((short8*)xlo)[gx] = l;
    }
}

__device__ __forceinline__ void load_to_lds16(const unsigned short* g, unsigned short* l) {
    __builtin_amdgcn_global_load_lds(
        (const __attribute__((address_space(1))) unsigned int*)(g),
        (__attribute__((address_space(3))) unsigned int*)(l),
        16, 0, 0);
}

// ---------------------------------------------------------------------------
// DMA GEMM: B via global_load_lds from pre-tiled planes (double-buffered LDS,
// 1 barrier per K-step); A direct global->VGPR fragment loads, prefetched.
// 4 waves: wm in {0,32}, wn in {0,64}; 2x4 grid of 16x16x32 MFMA, 3 per tile.
// ---------------------------------------------------------------------------
__global__ __launch_bounds__(256) void moe_gemm_dma(
    const unsigned short* __restrict__ xhi, const unsigned short* __restrict__ xlo,
    const unsigned short* __restrict__ whi, const unsigned short* __restrict__ wlo,
    const float* __restrict__ bias, const int* __restrict__ ws,
    float* __restrict__ out)
{
    // XCD swizzle: bx = id&7 -> each XCD sticks to one 128-col W slice (~4MB = L2)
    const int bx  = blockIdx.x & 7;
    const int tix = blockIdx.x >> 3;
    if (tix >= ws[WS_NTILES]) return;
    const int e   = ws[WS_TILE_E + tix];
    const int m0  = ws[WS_TILE_M + tix];
    const int s0  = ws[WS_STARTS + e];
    const int cnt = ws[WS_STARTS + e + 1] - s0;
    const int n0  = bx * TN;

    __shared__ unsigned short Bhi[2][8 * 512];
    __shared__ unsigned short Blo[2][8 * 512];
    __shared__ int rows_s[TM];

    const int t = threadIdx.x;
    if (t < TM) {
        const int r = m0 + t;
        rows_s[t] = (r < cnt) ? ws[WS_PERM + s0 + r] : -1;
    }
    __syncthreads();

    const int lane = t & 63;
    const int wave = t >> 6;
    const int wm = (wave & 1) * 32;
    const int wn = (wave >> 1) * 64;

    // A fragment sources: lane holds row (tile*16 + lane&15), k-chunk (lane>>4)*8
    const unsigned short* aSrcHi[2];
    const unsigned short* aSrcLo[2];
#pragma unroll
    for (int mi = 0; mi < 2; ++mi) {
        int r = rows_s[wm + mi * 16 + (lane & 15)];
        if (r < 0) r = 0;  // garbage compute, store masked in epilogue
        const size_t off = (size_t)r * D_IN + ((lane >> 4) << 3);
        aSrcHi[mi] = xhi + off;
        aSrcLo[mi] = xlo + off;
    }

    // B DMA: wave w stages chunks c=4w..4w+3: tile=c>>1, plane=c&1
    const unsigned short* bsrc[4];
    const unsigned short* bpl[4];
    int btile[4];
#pragma unroll
    for (int i = 0; i < 4; ++i) {
        const int c = wave * 4 + i;
        btile[i] = c >> 1;
        bpl[i] = (c & 1) ? wlo : whi;
        bsrc[i] = bpl[i] + (size_t)(e * 64 + bx * 8 + btile[i]) * 16384 + lane * 8;
    }

    const float zf = 0.f;
    f32x4 acc[2][4];
#pragma unroll
    for (int mi = 0; mi < 2; ++mi)
#pragma unroll
        for (int nj = 0; nj < 4; ++nj)
            acc[mi][nj] = (f32x4){zf, zf, zf, zf};

    // prologue: DMA step 0 into buf0, preload A(0)
    short8 ah[2], al[2], ahn[2], aln[2];
#pragma unroll
    for (int mi = 0; mi < 2; ++mi) {
        ah[mi] = *(const short8*)aSrcHi[mi];
        al[mi] = *(const short8*)aSrcLo[mi];
        aSrcHi[mi] += 32;
        aSrcLo[mi] += 32;
    }
#pragma unroll
    for (int i = 0; i < 4; ++i) {
        load_to_lds16(bsrc[i], ((bpl[i] == whi) ? &Bhi[0][0] : &Blo[0][0]) + btile[i] * 512);
        bsrc[i] += 512;
    }

    for (int s = 0; s < 32; ++s) {
        const int cur = s & 1;
        __syncthreads();   // drains vmcnt(0): DMA(s) + A(s) complete, all waves past reads of buf[cur^1]
        if (s < 31) {
#pragma unroll
            for (int mi = 0; mi < 2; ++mi) {
                ahn[mi] = *(const short8*)aSrcHi[mi];
                aln[mi] = *(const short8*)aSrcLo[mi];
                aSrcHi[mi] += 32;
                aSrcLo[mi] += 32;
            }
#pragma unroll
            for (int i = 0; i < 4; ++i) {
                load_to_lds16(bsrc[i], ((bpl[i] == whi) ? &Bhi[cur ^ 1][0] : &Blo[cur ^ 1][0]) + btile[i] * 512);
                bsrc[i] += 512;
            }
        }
        short8 bh[4], bl[4];
#pragma unroll
        for (int i2 = 0; i2 < 4; ++i2) {
            const int boff = ((wn >> 4) + i2) * 512 + lane * 8;
            bh[i2] = *(const short8*)&Bhi[cur][boff];
            bl[i2] = *(const short8*)&Blo[cur][boff];
        }
#pragma unroll
        for (int mi = 0; mi < 2; ++mi)
#pragma unroll
            for (int nj = 0; nj < 4; ++nj) {
                acc[mi][nj] = __builtin_amdgcn_mfma_f32_16x16x32_bf16(ah[mi], bh[nj], acc[mi][nj], 0, 0, 0);
                acc[mi][nj] = __builtin_amdgcn_mfma_f32_16x16x32_bf16(ah[mi], bl[nj], acc[mi][nj], 0, 0, 0);
                acc[mi][nj] = __builtin_amdgcn_mfma_f32_16x16x32_bf16(al[mi], bh[nj], acc[mi][nj], 0, 0, 0);
            }
        if (s < 31) {
#pragma unroll
            for (int mi = 0; mi < 2; ++mi) { ah[mi] = ahn[mi]; al[mi] = aln[mi]; }
        }
    }

    // Epilogue (verified R2 layout): col=lane&15, row=(lane>>4)*4+reg
    const int cl = lane & 15;
    const int qd = lane >> 4;
    float bv[4];
#pragma unroll
    for (int nj = 0; nj < 4; ++nj)
        bv[nj] = bias[e * D_OUT + n0 + wn + nj * 16 + cl];
#pragma unroll
    for (int mi = 0; mi < 2; ++mi) {
#pragma unroll
        for (int reg = 0; reg < 4; ++reg) {
            const int mloc = wm + mi * 16 + qd * 4 + reg;
            const int r = rows_s[mloc];
            if (r >= 0) {
                float* orow = out + (size_t)r * D_OUT + n0 + wn + cl;
#pragma unroll
                for (int nj = 0; nj < 4; ++nj)
                    orow[nj * 16] = acc[mi][nj][reg] + bv[nj];
            }
        }
    }
}

// ---------------------------------------------------------------------------
// Fallback GEMM (R2, proven) for small ws_size.
// ---------------------------------------------------------------------------
__global__ __launch_bounds__(256) void moe_gemm_fb(
    const float* __restrict__ xs, const float* __restrict__ W,
    const float* __restrict__ bias, const int* __restrict__ ws,
    float* __restrict__ out)
{
    const int tix = blockIdx.y;
    if (tix >= ws[WS_NTILES]) return;
    const int e   = ws[WS_TILE_E + tix];
    const int m0  = ws[WS_TILE_M + tix];
    const int s0  = ws[WS_STARTS + e];
    const int cnt = ws[WS_STARTS + e + 1] - s0;
    const int n0  = blockIdx.x * TN;

    __shared__ short Ahi[TM * 32];
    __shared__ short Alo[TM * 32];
    __shared__ short Bhi[TN * 32];
    __shared__ short Blo[TN * 32];
    __shared__ int   rows_s[TM];

    const int t = threadIdx.x;
    if (t < TM) {
        const int r = m0 + t;
        rows_s[t] = (r < cnt) ? ws[WS_PERM + s0 + r] : -1;
    }
    __syncthreads();

    const int lane = t & 63;
    const int wave = t >> 6;
    const int wm = (wave & 1) * 32;
    const int wn = (wave >> 1) * 64;

    const float zf = 0.f;
    f32x4 acc[2][4];
#pragma unroll
    for (int mi = 0; mi < 2; ++mi)
#pragma unroll
        for (int nj = 0; nj < 4; ++nj)
            acc[mi][nj] = (f32x4){zf, zf, zf, zf};

    const float* Wb = W + (size_t)e * (D_OUT * (size_t)D_IN) + (size_t)n0 * D_IN;
    const int j  = t & 3;
    const int rr = t >> 2;
    const int arow = rows_s[rr];
    const float* aptr = (arow >= 0) ? (xs + (size_t)arow * D_IN + j * 8) : nullptr;
    const int aoff_st = (rr >> 4) * 512 + (j * 16 + (rr & 15)) * 8;

    for (int k0 = 0; k0 < D_IN; k0 += 32) {
        __syncthreads();
        {
            float4 v0 = make_float4(0.f, 0.f, 0.f, 0.f), v1 = v0;
            if (aptr) {
                v0 = *(const float4*)(aptr + k0);
                v1 = *(const float4*)(aptr + k0 + 4);
            }
            short8 h, l;
            cvt8(v0, v1, h, l);
            *(short8*)&Ahi[aoff_st] = h;
            *(short8*)&Alo[aoff_st] = l;
        }
#pragma unroll
        for (int i = 0; i < 2; ++i) {
            const int n   = i * 64 + rr;
            const int off = (n >> 4) * 512 + (j * 16 + (n & 15)) * 8;
            const float* q = Wb + (size_t)n * D_IN + k0 + j * 8;
            const float4 w0 = *(const float4*)q;
            const float4 w1 = *(const float4*)(q + 4);
            short8 h, l;
            cvt8(w0, w1, h, l);
            *(short8*)&Bhi[off] = h;
            *(short8*)&Blo[off] = l;
        }
        __syncthreads();

        short8 ah[2], al[2], bh[4], bl[4];
#pragma unroll
        for (int i2 = 0; i2 < 2; ++i2) {
            const int aoff = ((wm >> 4) + i2) * 512 + lane * 8;
            ah[i2] = *(const short8*)&Ahi[aoff];
            al[i2] = *(const short8*)&Alo[aoff];
        }
#pragma unroll
        for (int i2 = 0; i2 < 4; ++i2) {
            const int boff = ((wn >> 4) + i2) * 512 + lane * 8;
            bh[i2] = *(const short8*)&Bhi[boff];
            bl[i2] = *(const short8*)&Blo[boff];
        }
#pragma unroll
        for (int mi = 0; mi < 2; ++mi)
#pragma unroll
            for (int nj = 0; nj < 4; ++nj) {
                acc[mi][nj] = __builtin_amdgcn_mfma_f32_16x16x32_bf16(ah[mi], bh[nj], acc[mi][nj], 0, 0, 0);
                acc[mi][nj] = __builtin_amdgcn_mfma_f32_16x16x32_bf16(ah[mi], bl[nj], acc[mi][nj], 0, 0, 0);
                acc[mi][nj] = __builtin_amdgcn_mfma_f32_16x16x32_bf16(al[mi], bh[nj], acc[mi][nj], 0, 0, 0);
            }
    }

    const int cl = lane & 15;
    const int qd = lane >> 4;
    float bv[4];
#pragma unroll
    for (int nj = 0; nj < 4; ++nj)
        bv[nj] = bias[e * D_OUT + n0 + wn + nj * 16 + cl];
#pragma unroll
    for (int mi = 0; mi < 2; ++mi) {
#pragma unroll
        for (int reg = 0; reg < 4; ++reg) {
            const int mloc = wm + mi * 16 + qd * 4 + reg;
            const int r = rows_s[mloc];
            if (r >= 0) {
                float* orow = out + (size_t)r * D_OUT + n0 + wn + cl;
#pragma unroll
                for (int nj = 0; nj < 4; ++nj)
                    orow[nj * 16] = acc[mi][nj][reg] + bv[nj];
            }
        }
    }
}

// ---------------------------------------------------------------------------
__global__ void meta_float_kernel(const int* __restrict__ mxs,
                                  const int* __restrict__ actions,
                                  float* __restrict__ out) {
    const int i = blockIdx.x * 256 + threadIdx.x;
    if (i < BATCH) {
        out[BATCH * D_OUT + i] = (float)mxs[i];
        out[BATCH * D_OUT + BATCH + i] = (float)actions[i];
    }
}

__global__ void meta_raw64_kernel(const int* __restrict__ mxs,
                                  const int* __restrict__ actions,
                                  float* __restrict__ out) {
    const int i = blockIdx.x * 256 + threadIdx.x;
    if (i < BATCH) {
        out[BATCH * D_OUT + i] = (float)mxs[i];
        long long* a64 = (long long*)(out + BATCH * D_OUT + BATCH);
        a64[i] = (long long)actions[i];
    }
}

extern "C" void kernel_launch(void* const* d_in, const int* in_sizes, int n_in,
                              void* d_out, int out_size, void* d_ws, size_t ws_size,
                              hipStream_t stream) {
    const float* xs      = (const float*)d_in[0];
    const int*   mxs     = (const int*)d_in[1];
    const int*   actions = (const int*)d_in[2];
    const float* W       = (const float*)d_in[3];
    const float* bias    = (const float*)d_in[4];
    float* out = (float*)d_out;
    int*   ws  = (int*)d_ws;

    group_kernel<<<1, 256, 0, stream>>>(actions, ws);

    if (ws_size >= WS_NEED) {
        unsigned short* whi = (unsigned short*)((char*)d_ws + OFF_WHI);
        unsigned short* wlo = (unsigned short*)((char*)d_ws + OFF_WLO);
        unsigned short* xhi = (unsigned short*)((char*)d_ws + OFF_XHI);
        unsigned short* xlo = (unsigned short*)((char*)d_ws + OFF_XLO);
        convert_kernel<<<(W_CHUNKS + X_CHUNKS) / 256, 256, 0, stream>>>(xs, W, whi, wlo, xhi, xlo);
        moe_gemm_dma<<<8 * MAX_TILES, 256, 0, stream>>>(xhi, xlo, whi, wlo, bias, ws, out);
    } else {
        dim3 grid(D_OUT / TN, MAX_TILES, 1);
        moe_gemm_fb<<<grid, 256, 0, stream>>>(xs, W, bias, ws, out);
    }

    const int metaOff = BATCH * D_OUT;
    if (out_size >= metaOff + 3 * BATCH) {
        meta_raw64_kernel<<<(BATCH + 255) / 256, 256, 0, stream>>>(mxs, actions, out);
    } else if (out_size >= metaOff + 2 * BATCH) {
        meta_float_kernel<<<(BATCH + 255) / 256, 256, 0, stream>>>(mxs, actions, out);
    }
}